// Round 12
// baseline (152.881 us; speedup 1.0000x reference)
//
#include <hip/hip_runtime.h>
#include <hip/hip_bf16.h>

// GraphConvPooling: y = (A @ x) @ W + b ; pooled = max_rows(y) ; MLP(tanh,tanh,lin)
// A is DEDUPLICATED 0/1 adjacency. Reassociated: y = A@(x@W)+b.
//
// Rounds 4-10 proved the sparse gather is walled at ~45-65us by L1 line-miss
// concurrency (~0.15 lines/cy/CU). Round 11+: DENSE MFMA. A-tile (64x1024 bf16)
// built in LDS by plain stores (duplicates overwrite 1.0 -> dedup free);
// xw split hi+lo bf16 (error ~2e-5); A@xw via mfma_f32_32x32x16_bf16.
// Round-12 fix: fused-MLP tail now covers all 64 graphs (8 waves x 8 graphs;
// round 11 used w*4+gg from the 16-wave version -> graphs 32-63 never written).
//
// Tier A (ws >= ~34MB): bin -> xwt(frag-major hi/lo) -> agg_mfma(+fused MLP)
// Tier B (ws >= ~8.4MB): round-3 proven bitmask path. Tier C: zero-ws fused.
//
// B=64 graphs, N=1024 nodes/graph, D=64. edge_index arrives as INT32.

#define NNODES 65536
#define NGRAPH 64
#define NLOCAL 1024
#define DIM 64
#define MASK_WORDS 32
#define NBIN 256        // bin blocks
#define NBUCKET 512     // 64 graphs x 8 chunks of 128 rows
#define SEGCAP 32       // slots per (bin,bucket): mean 8, P(>32)~1e-11
#define AK 1032         // Abf row stride (bf16): 1024 + 8 pad

typedef __attribute__((ext_vector_type(8))) short bf16x8;
typedef __attribute__((ext_vector_type(16))) float f32x16;

__device__ __forceinline__ unsigned f2ord(float f) {
    unsigned u = __float_as_uint(f);
    return (u & 0x80000000u) ? ~u : (u | 0x80000000u);
}
__device__ __forceinline__ float ord2f(unsigned u) {
    return (u & 0x80000000u) ? __uint_as_float(u & 0x7FFFFFFFu)
                             : __uint_as_float(~u);
}

__global__ __launch_bounds__(256) void clear_kernel(uint4* __restrict__ p, int n4)
{
    int i = blockIdx.x * 256 + threadIdx.x;
    int stride = gridDim.x * 256;
    uint4 z = {0u, 0u, 0u, 0u};
    for (; i < n4; i += stride) p[i] = z;
}

// Privatized binning (proven r6-r10): block b owns seg[b][bucket][SEGCAP],
// plain stores only. Also zeroes pooled+done. bucket = g*8 + (s_loc>>7).
__global__ __launch_bounds__(256) void bin_kernel(
    const int* __restrict__ ei, int E,
    unsigned* __restrict__ seg, unsigned short* __restrict__ segcnt,
    unsigned* __restrict__ pooled_u, unsigned* __restrict__ done)
{
    __shared__ unsigned off[NBUCKET];
    int tid = threadIdx.x;
    off[tid] = 0u;
    off[tid + 256] = 0u;
    if (blockIdx.x < 16) pooled_u[blockIdx.x * 256 + tid] = 0u;
    if (blockIdx.x == 16 && tid == 0) *done = 0u;
    __syncthreads();
    int perblk = (E + NBIN - 1) / NBIN;
    int e0 = blockIdx.x * perblk;
    int e1 = min(e0 + perblk, E);
    unsigned* myseg = seg + (size_t)blockIdx.x * NBUCKET * SEGCAP;
    for (int e = e0 + tid; e < e1; e += 256) {
        int s = ei[e];
        int t = ei[E + e] & (NLOCAL - 1);
        int sl = s & (NLOCAL - 1);
        int bk = ((s >> 10) << 3) | (sl >> 7);
        unsigned slot = atomicAdd(&off[bk], 1u);
        if (slot < SEGCAP) myseg[bk * SEGCAP + slot] = (unsigned)((sl << 10) | t);
    }
    __syncthreads();
    unsigned c0 = off[tid], c1 = off[tid + 256];
    segcnt[blockIdx.x * NBUCKET + tid]       = (unsigned short)(c0 < SEGCAP ? c0 : SEGCAP);
    segcnt[blockIdx.x * NBUCKET + tid + 256] = (unsigned short)(c1 < SEGCAP ? c1 : SEGCAP);
}

// xwT = (x@W)^T as bf16 hi + lo residual, in MFMA-fragment-major layout:
// per graph: [kc(16)][ks(4)][mt(2)][lane(64)][j(8)] where
// c = mt*32 + (lane&31), k = kc*64 + ks*16 + (lane>>5)*8 + j.
__global__ __launch_bounds__(256) void xwt_kernel(
    const float* __restrict__ x, const float* __restrict__ W,
    unsigned short* __restrict__ xwFhi, unsigned short* __restrict__ xwFlo)
{
    __shared__ float4 xlds[64 * 16];        // 16KB
    __shared__ unsigned short outH[4096];   // 8KB
    __shared__ unsigned short outL[4096];   // 8KB
    int tid = threadIdx.x;
    int b = blockIdx.x;
    int xcd = b & 7, idx = b >> 3;
    int g = ((idx >> 4) << 3) | xcd;        // g%8 == xcd (matches agg's map)
    int kc = idx & 15;
    size_t row0 = ((size_t)g << 10) + (size_t)kc * 64;

    const float4* xg4 = (const float4*)(x + row0 * DIM);
    for (int i = tid; i < 1024; i += 256) xlds[i] = xg4[i];
    int c = tid & 63;
    float wreg[64];
    #pragma unroll
    for (int k = 0; k < 64; ++k) wreg[k] = W[k * DIM + c];  // coalesced
    __syncthreads();

    int rgrp = tid >> 6;
    int mt = c >> 5;
    #pragma unroll
    for (int i = 0; i < 16; ++i) {
        int r = rgrp * 16 + i;              // k-row within this kc chunk
        float acc = 0.f;
        #pragma unroll
        for (int q = 0; q < 16; ++q) {
            float4 xv = xlds[r * 16 + q];   // wave-uniform broadcast
            acc = fmaf(xv.x, wreg[4 * q + 0], acc);
            acc = fmaf(xv.y, wreg[4 * q + 1], acc);
            acc = fmaf(xv.z, wreg[4 * q + 2], acc);
            acc = fmaf(xv.w, wreg[4 * q + 3], acc);
        }
        // RNE split: acc = hi(bf16) + lo(bf16) + O(2^-16 rel)
        unsigned u = __float_as_uint(acc);
        unsigned hr = (u + 0x7FFFu + ((u >> 16) & 1u)) >> 16;
        float hif = __uint_as_float(hr << 16);
        float lof = acc - hif;
        unsigned ul = __float_as_uint(lof);
        unsigned lr = (ul + 0x7FFFu + ((ul >> 16) & 1u)) >> 16;
        int ks = r >> 4;
        int lslot = (c & 31) | (((r >> 3) & 1) << 5);
        int o = ((ks * 2 + mt) * 64 + lslot) * 8 + (r & 7);
        outH[o] = (unsigned short)hr;
        outL[o] = (unsigned short)lr;
    }
    __syncthreads();
    size_t gbase = ((size_t)g * 16 + kc) * 4096;
    uint4* dh = (uint4*)(xwFhi + gbase);
    uint4* dl = (uint4*)(xwFlo + gbase);
    const uint4* sh = (const uint4*)outH;
    const uint4* sl4 = (const uint4*)outL;
    for (int i = tid; i < 512; i += 256) { dh[i] = sh[i]; dl[i] = sl4[i]; }
}

// One block per (graph, 64-dest chunk): 1024 blocks x 512 thr (8 waves).
// Wave role: mt = w>>2 (xw-col 32-tile), kslot = w&3 (k-stride). Per kc (16):
// 2 coalesced 1KB global A-frag loads (hi,lo) + 2 LDS B-frags + 4 MFMA. No
// barriers in the K-loop. Deterministic kslot-ordered combine, max, fused MLP.
__global__ __launch_bounds__(512, 1) void agg_mfma_kernel(
    const unsigned short* __restrict__ xwFhi, const unsigned short* __restrict__ xwFlo,
    const float* __restrict__ bias,
    const unsigned* __restrict__ seg, const unsigned short* __restrict__ segcnt,
    unsigned* __restrict__ pooled_u, unsigned* __restrict__ done,
    const float* __restrict__ w1, const float* __restrict__ b1,
    const float* __restrict__ w2, const float* __restrict__ b2,
    const float* __restrict__ w3, const float* __restrict__ b3,
    float* __restrict__ out)
{
    __shared__ unsigned short Abf[64 * AK];   // 129 KiB; reused as redf after K-loop
    __shared__ unsigned lastflag;

    int tid = threadIdx.x;
    int lane = tid & 63, w = tid >> 6;
    int b = blockIdx.x;
    int xcd = b & 7, rest = b >> 3;
    int chunk = rest & 15, gh = rest >> 4;
    int g = (gh << 3) | xcd;                 // g%8 == blockIdx%8 -> XCD locality
    int bk = (g << 3) | (chunk >> 1);        // 128-row bucket
    int half = chunk & 1;

    uint4 z4 = {0u, 0u, 0u, 0u};
    for (int i = tid; i < 64 * AK * 2 / 16; i += 512) ((uint4*)Abf)[i] = z4;
    __syncthreads();

    // build dense A-tile: plain bf16-1.0 stores; duplicates overwrite (dedup free)
    for (int idx = tid; idx < NBIN * SEGCAP; idx += 512) {
        int sb = idx >> 5, sl = idx & 31;
        int n = segcnt[sb * NBUCKET + bk];
        if (sl < n) {
            unsigned pk = seg[((size_t)sb * NBUCKET + bk) * SEGCAP + sl];
            int r = (pk >> 10) & 127;
            if ((r >> 6) == half)
                Abf[(r & 63) * AK + (pk & (NLOCAL - 1))] = 0x3F80;  // bf16 1.0
        }
    }
    __syncthreads();

    int mt = w >> 2, kslot = w & 3;
    f32x16 acc0, acc1;
    #pragma unroll
    for (int i = 0; i < 16; ++i) { acc0[i] = 0.f; acc1[i] = 0.f; }

    const unsigned short* Ahb = xwFhi + (size_t)g * 65536;
    const unsigned short* Alb = xwFlo + (size_t)g * 65536;
    for (int kc = 0; kc < 16; ++kc) {
        int foff = ((kc * 4 + kslot) * 2 + mt) * 512 + lane * 8;
        bf16x8 Ah = *(const bf16x8*)(Ahb + foff);     // coalesced 1KB/wave
        bf16x8 Al = *(const bf16x8*)(Alb + foff);
        int k0 = kc * 64 + kslot * 16 + ((lane >> 5) * 8);
        bf16x8 B0 = *(const bf16x8*)(Abf + (lane & 31) * AK + k0);        // nt=0
        bf16x8 B1 = *(const bf16x8*)(Abf + (32 + (lane & 31)) * AK + k0); // nt=1
        acc0 = __builtin_amdgcn_mfma_f32_32x32x16_bf16(Ah, B0, acc0, 0, 0, 0);
        acc0 = __builtin_amdgcn_mfma_f32_32x32x16_bf16(Al, B0, acc0, 0, 0, 0);
        acc1 = __builtin_amdgcn_mfma_f32_32x32x16_bf16(Ah, B1, acc1, 0, 0, 0);
        acc1 = __builtin_amdgcn_mfma_f32_32x32x16_bf16(Al, B1, acc1, 0, 0, 0);
    }
    __syncthreads();   // all Abf reads done -> alias as redf

    float* redf = (float*)Abf;   // [mt(2)][nt(2)][row(32)][dest(32)] = 16KB
    for (int s = 0; s < 4; ++s) {   // deterministic kslot-ordered partial sum
        if (kslot == s) {
            #pragma unroll
            for (int nt = 0; nt < 2; ++nt) {
                #pragma unroll
                for (int rg = 0; rg < 16; ++rg) {
                    float v = nt ? acc1[rg] : acc0[rg];
                    int row = (rg & 3) + 8 * (rg >> 2) + 4 * (lane >> 5);  // m101 C/D map
                    int idx = (mt * 2 + nt) * 1024 + row * 32 + (lane & 31);
                    if (s == 0) redf[idx] = v; else redf[idx] += v;
                }
            }
        }
        __syncthreads();
    }

    // max over the 64 dests for each of the 64 xw-cols
    int cm = tid >> 3, part = tid & 7;
    float m = -INFINITY;
    #pragma unroll
    for (int nt = 0; nt < 2; ++nt) {
        #pragma unroll
        for (int u = 0; u < 4; ++u) {
            int d = part * 4 + u;
            m = fmaxf(m, redf[((cm >> 5) * 2 + nt) * 1024 + (cm & 31) * 32 + d]);
        }
    }
    m = fmaxf(m, __shfl_xor(m, 1, 64));
    m = fmaxf(m, __shfl_xor(m, 2, 64));
    m = fmaxf(m, __shfl_xor(m, 4, 64));
    if (part == 0) atomicMax(&pooled_u[g * DIM + cm], f2ord(m));
    __syncthreads();   // drain all waves' atomics before signaling done

    if (tid == 0) {
        __threadfence();
        unsigned v = atomicAdd(done, 1u);
        lastflag = (v == 1023u) ? 1u : 0u;   // grid = 1024 blocks
    }
    __syncthreads();
    if (lastflag) {
        // 8 waves x 8 graphs each = all 64 graphs (round-12 fix)
        for (int gg = 0; gg < 8; ++gg) {
            int g2 = w * 8 + gg;
            float pl = ord2f(atomicOr(&pooled_u[g2 * DIM + lane], 0u)) + bias[lane];
            float h = b1[lane];
            for (int k2 = 0; k2 < 64; ++k2) {
                float a = __shfl(pl, k2, 64);
                h = fmaf(a, w1[k2 * DIM + lane], h);
            }
            h = tanhf(h);
            float h2 = b2[lane];
            for (int k2 = 0; k2 < 64; ++k2) {
                float a = __shfl(h, k2, 64);
                h2 = fmaf(a, w2[k2 * DIM + lane], h2);
            }
            h2 = tanhf(h2);
            float v2 = h2 * w3[lane];
            #pragma unroll
            for (int o = 32; o; o >>= 1) v2 += __shfl_down(v2, o, 64);
            if (lane == 0) out[g2] = v2 + b3[0];
        }
    }
}

// ---- Tier B (round-3 proven): global bitmask + ffs + shfl matvec ----
__global__ __launch_bounds__(256) void scatter_kernel(
    const int* __restrict__ ei, unsigned* __restrict__ mask, int E)
{
    int e = blockIdx.x * 256 + threadIdx.x;
    if (e >= E) return;
    int start = ei[e];
    int col   = ei[E + e] & (NLOCAL - 1);
    atomicOr(&mask[(size_t)start * MASK_WORDS + (col >> 5)], 1u << (col & 31));
}

__global__ __launch_bounds__(256) void agg_kernel(
    const float* __restrict__ x, const float* __restrict__ weight,
    const float* __restrict__ bias, const unsigned* __restrict__ mask,
    unsigned* __restrict__ pooled_u)
{
    __shared__ float Wlds[DIM * DIM];
    __shared__ float blds[DIM];
    int tid = threadIdx.x;
    for (int i = tid; i < DIM * DIM; i += 256) Wlds[i] = weight[i];
    if (tid < DIM) blds[tid] = bias[tid];
    __syncthreads();
    int lane = tid & 63;
    int wave = tid >> 6;
    int rowbase = blockIdx.x * 64 + wave * 16;
    int g = rowbase >> 10;
    const float* xg = x + ((size_t)g << 10) * DIM;
    float vmax = -INFINITY;
    for (int rr = 0; rr < 16; ++rr) {
        int row = rowbase + rr;
        const unsigned* mrow = mask + (size_t)row * MASK_WORDS;
        float acc = 0.f;
        for (int w = 0; w < MASK_WORDS; ++w) {
            unsigned bits = mrow[w];
            while (bits) {
                int b = __ffs(bits) - 1;
                bits &= bits - 1;
                acc += xg[(size_t)(w * 32 + b) * DIM + lane];
            }
        }
        float y = blds[lane];
        for (int k = 0; k < DIM; ++k) {
            float a = __shfl(acc, k, 64);
            y = fmaf(a, Wlds[k * DIM + lane], y);
        }
        vmax = fmaxf(vmax, y);
    }
    atomicMax(&pooled_u[g * DIM + lane], f2ord(vmax));
}

__global__ __launch_bounds__(64) void mlp_kernel(
    const unsigned* __restrict__ pooled_u,
    const float* __restrict__ w1, const float* __restrict__ b1,
    const float* __restrict__ w2, const float* __restrict__ b2,
    const float* __restrict__ w3, const float* __restrict__ b3,
    float* __restrict__ out)
{
    __shared__ float buf[DIM];
    __shared__ float buf2[DIM];
    int g = blockIdx.x, l = threadIdx.x;
    buf[l] = ord2f(pooled_u[g * DIM + l]);
    __syncthreads();
    float h = b1[l];
    for (int k = 0; k < DIM; ++k) h = fmaf(buf[k], w1[k * DIM + l], h);
    buf2[l] = tanhf(h);
    __syncthreads();
    float h2 = b2[l];
    for (int k = 0; k < DIM; ++k) h2 = fmaf(buf2[k], w2[k * DIM + l], h2);
    h2 = tanhf(h2);
    float v = h2 * w3[l];
    #pragma unroll
    for (int off = 32; off; off >>= 1) v += __shfl_down(v, off, 64);
    if (l == 0) out[g] = v + b3[0];
}

// ---- Tier C: fused zero-workspace fallback ----
__global__ __launch_bounds__(1024) void fused_kernel(
    const float* __restrict__ x, const int* __restrict__ ei, int E,
    const float* __restrict__ weight, const float* __restrict__ bias,
    const float* __restrict__ w1, const float* __restrict__ b1,
    const float* __restrict__ w2, const float* __restrict__ b2,
    const float* __restrict__ w3, const float* __restrict__ b3,
    float* __restrict__ out)
{
    __shared__ unsigned mask[256 * MASK_WORDS];
    __shared__ float Wlds[DIM * DIM];
    __shared__ float blds[DIM];
    __shared__ float red[16 * DIM];
    __shared__ float pool[DIM];
    __shared__ float hbuf[DIM];
    int tid = threadIdx.x;
    int g = blockIdx.x;
    int lane = tid & 63;
    int wave = tid >> 6;
    const float* xg = x + ((size_t)g << 10) * DIM;
    for (int i = tid; i < DIM * DIM; i += 1024) Wlds[i] = weight[i];
    if (tid < DIM) blds[tid] = bias[tid];
    float vmax = -INFINITY;
    for (int chunk = 0; chunk < NLOCAL / 256; ++chunk) {
        int row0 = chunk * 256;
        __syncthreads();
        for (int i = tid; i < 256 * MASK_WORDS; i += 1024) mask[i] = 0u;
        __syncthreads();
        int lo = (g << 10) + row0, hi = lo + 256;
        for (int e = tid; e < E; e += 1024) {
            int s = ei[e];
            if (s >= lo && s < hi) {
                int t = ei[E + e] & (NLOCAL - 1);
                atomicOr(&mask[(s - lo) * MASK_WORDS + (t >> 5)], 1u << (t & 31));
            }
        }
        __syncthreads();
        for (int rr = 0; rr < 256 / 16; ++rr) {
            int row = wave * (256 / 16) + rr;
            float acc = 0.f;
            for (int w = 0; w < MASK_WORDS; ++w) {
                unsigned bits = mask[row * MASK_WORDS + w];
                while (bits) {
                    int b = __ffs(bits) - 1;
                    bits &= bits - 1;
                    acc += xg[(size_t)(w * 32 + b) * DIM + lane];
                }
            }
            float y = blds[lane];
            for (int k = 0; k < 64; ++k) {
                float a = __shfl(acc, k, 64);
                y = fmaf(a, Wlds[k * DIM + lane], y);
            }
            vmax = fmaxf(vmax, y);
        }
    }
    red[wave * DIM + lane] = vmax;
    __syncthreads();
    if (tid < DIM) {
        float m = red[tid];
        #pragma unroll
        for (int w = 1; w < 16; ++w) m = fmaxf(m, red[w * DIM + tid]);
        pool[tid] = m;
    }
    __syncthreads();
    if (tid < DIM) {
        float h = b1[tid];
        for (int k = 0; k < DIM; ++k) h = fmaf(pool[k], w1[k * DIM + tid], h);
        hbuf[tid] = tanhf(h);
    }
    __syncthreads();
    if (tid < DIM) {
        float h2 = b2[tid];
        for (int k = 0; k < DIM; ++k) h2 = fmaf(hbuf[k], w2[k * DIM + tid], h2);
        h2 = tanhf(h2);
        red[tid] = h2 * w3[tid];
    }
    __syncthreads();
    if (tid == 0) {
        float v = b3[0];
        for (int k = 0; k < DIM; ++k) v += red[k];
        out[g] = v;
    }
}

extern "C" void kernel_launch(void* const* d_in, const int* in_sizes, int n_in,
                              void* d_out, int out_size, void* d_ws, size_t ws_size,
                              hipStream_t stream)
{
    const float* x      = (const float*)d_in[0];
    const int*   ei     = (const int*)d_in[1];   // int32 (harness converts)
    const float* weight = (const float*)d_in[4];
    const float* bias   = (const float*)d_in[5];
    const float* w1     = (const float*)d_in[6];
    const float* b1     = (const float*)d_in[7];
    const float* w2     = (const float*)d_in[8];
    const float* b2     = (const float*)d_in[9];
    const float* w3     = (const float*)d_in[10];
    const float* b3     = (const float*)d_in[11];
    float* out = (float*)d_out;

    const int E = in_sizes[1] / 2;

    // Tier A: [pooled 16KB | done 64B | segcnt 256KB | seg 16MB | xwFhi 8MB | xwFlo 8MB]
    const size_t PL_BYTES  = (size_t)NGRAPH * DIM * 4 + 64;
    const size_t SC_BYTES  = (size_t)NBIN * NBUCKET * 2;
    const size_t SEG_BYTES = (size_t)NBIN * NBUCKET * SEGCAP * 4;
    const size_t XF_BYTES  = (size_t)NGRAPH * 65536 * 2;            // 8 MB each
    const size_t need_A = PL_BYTES + SC_BYTES + SEG_BYTES + 2 * XF_BYTES;
    const size_t MASKW  = (size_t)NNODES * MASK_WORDS;
    const size_t need_B = MASKW * 4 + PL_BYTES;

    if (d_ws != nullptr && ws_size >= need_A) {
        char* base = (char*)d_ws;
        unsigned*       pooled_u = (unsigned*)base;
        unsigned*       done     = (unsigned*)(base + (size_t)NGRAPH * DIM * 4);
        unsigned short* segcnt   = (unsigned short*)(base + PL_BYTES);
        unsigned*       seg      = (unsigned*)(base + PL_BYTES + SC_BYTES);
        unsigned short* xwFhi    = (unsigned short*)(base + PL_BYTES + SC_BYTES + SEG_BYTES);
        unsigned short* xwFlo    = (unsigned short*)(base + PL_BYTES + SC_BYTES + SEG_BYTES + XF_BYTES);

        bin_kernel<<<NBIN, 256, 0, stream>>>(ei, E, seg, segcnt, pooled_u, done);
        xwt_kernel<<<1024, 256, 0, stream>>>(x, weight, xwFhi, xwFlo);
        agg_mfma_kernel<<<1024, 512, 0, stream>>>(
            xwFhi, xwFlo, bias, seg, segcnt, pooled_u, done,
            w1, b1, w2, b2, w3, b3, out);
    } else if (d_ws != nullptr && ws_size >= need_B) {
        unsigned* mask     = (unsigned*)d_ws;
        unsigned* pooled_u = mask + MASKW;
        clear_kernel<<<1024, 256, 0, stream>>>((uint4*)mask, (int)((MASKW * 4 + 16384) / 16));
        scatter_kernel<<<(E + 255) / 256, 256, 0, stream>>>(ei, mask, E);
        agg_kernel<<<NNODES / 64, 256, 0, stream>>>(x, weight, bias, mask, pooled_u);
        mlp_kernel<<<NGRAPH, DIM, 0, stream>>>(pooled_u, w1, b1, w2, b2, w3, b3, out);
    } else {
        fused_kernel<<<NGRAPH, 1024, 0, stream>>>(
            x, ei, E, weight, bias, w1, b1, w2, b2, w3, b3, out);
    }
}